// Round 1
// baseline (61417.474 us; speedup 1.0000x reference)
//
#include <hip/hip_runtime.h>
#include <math.h>

// Problem constants (fixed by setup_inputs)
#define NWG 256
#define NT  512
#define BB  64      // batch
#define TT  512     // seq len
#define HH  512     // hidden
#define RR  1024    // decode rows = B*S
#define HOR 64      // horizon
#define WST 520     // LDS row stride (floats): 520%32=8 -> 2-way bank alias (free)

// Persistent state in device globals (re-initialized every launch)
__device__ float g_h0[2][BB][HH];
__device__ float g_h1[2][BB][HH];
__device__ float g_c0[BB][HH];
__device__ float g_c1[BB][HH];
__device__ float g_H0[2][RR][HH];
__device__ float g_H1[2][RR][HH];
__device__ float g_C0[RR][HH];
__device__ float g_C1[RR][HH];
__device__ float g_u[RR];

__device__ __forceinline__ float sigf(float v) { return 1.0f / (1.0f + expf(-v)); }

// 512-length dot, 4 independent FMA chains for ILP
__device__ __forceinline__ float dot512(const float* h, const float* w) {
  const float4* hp = (const float4*)h;
  const float4* wp = (const float4*)w;
  float ax = 0.f, ay = 0.f, az = 0.f, aw = 0.f;
#pragma unroll 8
  for (int k = 0; k < HH / 4; ++k) {
    float4 a = hp[k];
    float4 b = wp[k];
    ax = fmaf(a.x, b.x, ax);
    ay = fmaf(a.y, b.y, ay);
    az = fmaf(a.z, b.z, az);
    aw = fmaf(a.w, b.w, aw);
  }
  return (ax + ay) + (az + aw);
}

// Grid barrier: monotonically increasing counter, agent-scope release/acquire.
// Counter reset to 0 by hipMemsetAsync each kernel_launch.
__device__ __forceinline__ void gridbar(unsigned* cnt, unsigned& phase) {
  __syncthreads();
  phase += NWG;
  if (threadIdx.x == 0) {
    __hip_atomic_fetch_add(cnt, 1u, __ATOMIC_ACQ_REL, __HIP_MEMORY_SCOPE_AGENT);
    while (__hip_atomic_load(cnt, __ATOMIC_ACQUIRE, __HIP_MEMORY_SCOPE_AGENT) < phase)
      __builtin_amdgcn_s_sleep(2);
  }
  __syncthreads();
}

__device__ __forceinline__ float cellupd(float iv, float fv, float gv, float ov, float& c) {
  c = sigf(fv) * c + sigf(iv) * tanhf(gv);
  return sigf(ov) * tanhf(c);
}

__global__ __launch_bounds__(NT, 1) void lstm_all(
    const float* __restrict__ x, const float* __restrict__ init_input,
    const float* __restrict__ w_ih0, const float* __restrict__ w_hh0,
    const float* __restrict__ b0, const float* __restrict__ w_ih1,
    const float* __restrict__ w_hh1, const float* __restrict__ b1,
    const float* __restrict__ w_out, const float* __restrict__ b_out,
    float* __restrict__ out, unsigned* cnt) {
  const int wg = blockIdx.x;
  const int tid = threadIdx.x;
  const int jh0 = wg * 2;  // this WG owns hidden cols jh0, jh0+1 (x4 gates)

  __shared__ __align__(16) float s_whh0[8 * WST];
  __shared__ __align__(16) float s_wih1[8 * WST];
  __shared__ __align__(16) float s_whh1[8 * WST];
  __shared__ float s_gb[64 * 8];   // gate exchange: [row-sub][gate*2+q]
  __shared__ __align__(16) float s_wout[HH];
  __shared__ float s_wih0[8], s_b0[8], s_b1[8];
  __shared__ float s_red[8];

  // ---- load persistent weight rows into LDS (gate-major: idx = gate*2+q) ----
  for (int r8 = 0; r8 < 8; ++r8) {
    int gate = r8 >> 1, q = r8 & 1;
    int j = gate * HH + jh0 + q;
    s_whh0[r8 * WST + tid] = w_hh0[j * HH + tid];
    s_wih1[r8 * WST + tid] = w_ih1[j * HH + tid];
    s_whh1[r8 * WST + tid] = w_hh1[j * HH + tid];
  }
  if (tid < 8) {
    int gate = tid >> 1, q = tid & 1;
    int j = gate * HH + jh0 + q;
    s_wih0[tid] = w_ih0[j];
    s_b0[tid] = b0[j];
    s_b1[tid] = b1[j];
  }
  s_wout[tid] = w_out[tid];

  // ---- zero-init encoder state ----
  {
    int idx = wg * NT + tid;  // 0..131071
    if (idx < 2 * BB * HH) {
      (&g_h0[0][0][0])[idx] = 0.f;
      (&g_h1[0][0][0])[idx] = 0.f;
    }
    if (idx < BB * HH) {
      (&g_c0[0][0])[idx] = 0.f;
      (&g_c1[0][0])[idx] = 0.f;
    }
  }
  unsigned phase = 0;
  gridbar(cnt, phase);

  const int g2q = tid & 7;          // gate*2+q
  const int gate = (tid >> 1) & 3;
  const int q = tid & 1;

  // ---- encoder: 513 ticks, L1 pipelined one step behind L0 ----
  for (int tk = 1; tk <= TT + 1; ++tk) {
    const float* h0p = &g_h0[(tk - 1) & 1][0][0];  // h0^{tk-1}
    const int b = tid >> 3;
    if (tk <= TT) {  // L0 step tk
      float acc = dot512(h0p + b * HH, s_whh0 + g2q * WST);
      acc += x[b * TT + (tk - 1)] * s_wih0[g2q] + s_b0[g2q];
      s_gb[b * 8 + g2q] = acc;
      __syncthreads();
      if (gate == 0) {
        int jh = jh0 + q;
        float iv = s_gb[b * 8 + q], fv = s_gb[b * 8 + 2 + q];
        float gv = s_gb[b * 8 + 4 + q], ov = s_gb[b * 8 + 6 + q];
        float c = g_c0[b][jh];
        g_h0[tk & 1][b][jh] = cellupd(iv, fv, gv, ov, c);
        g_c0[b][jh] = c;
      }
      __syncthreads();
    }
    if (tk >= 2) {  // L1 step tk-1 (consumes h0^{tk-1}, h1^{tk-2})
      const float* h1p = &g_h1[tk & 1][0][0];  // h1^{tk-2}
      float acc = dot512(h0p + b * HH, s_wih1 + g2q * WST) +
                  dot512(h1p + b * HH, s_whh1 + g2q * WST) + s_b1[g2q];
      s_gb[b * 8 + g2q] = acc;
      __syncthreads();
      if (gate == 0) {
        int jh = jh0 + q;
        float iv = s_gb[b * 8 + q], fv = s_gb[b * 8 + 2 + q];
        float gv = s_gb[b * 8 + 4 + q], ov = s_gb[b * 8 + 6 + q];
        float c = g_c1[b][jh];
        g_h1[(tk - 1) & 1][b][jh] = cellupd(iv, fv, gv, ov, c);
        g_c1[b][jh] = c;
      }
      __syncthreads();
    }
    gridbar(cnt, phase);
  }

  // ---- expand final states over n_samples: row r = b*16+s ----
  {
    int gt = wg * NT + tid;          // 0..131071 == RR*HH/4 float4 slots
    int r = gt >> 7, k4 = gt & 127;  // HH/4 = 128
    int b = r >> 4;
    ((float4*)&g_H0[0][r][0])[k4] = ((const float4*)&g_h0[0][b][0])[k4];
    ((float4*)&g_C0[r][0])[k4] = ((const float4*)&g_c0[b][0])[k4];
    ((float4*)&g_H1[0][r][0])[k4] = ((const float4*)&g_h1[0][b][0])[k4];
    ((float4*)&g_C1[r][0])[k4] = ((const float4*)&g_c1[b][0])[k4];
    if (gt < RR) g_u[gt] = init_input[gt];
  }
  gridbar(cnt, phase);

  // ---- autoregressive decode: 64 steps x (L0, L1, pred) ----
  for (int d = 0; d < HOR; ++d) {
    const int cur = d & 1, nxt = cur ^ 1;
    // L0: gates over 1024 rows in 16 blocks of 64
    for (int rb = 0; rb < 16; ++rb) {
      int rsub = tid >> 3;
      int rr = rb * 64 + rsub;
      float acc = dot512(&g_H0[cur][rr][0], s_whh0 + g2q * WST);
      acc += g_u[rr] * s_wih0[g2q] + s_b0[g2q];
      s_gb[rsub * 8 + g2q] = acc;
      __syncthreads();
      if (gate == 0) {
        int jh = jh0 + q;
        float iv = s_gb[rsub * 8 + q], fv = s_gb[rsub * 8 + 2 + q];
        float gv = s_gb[rsub * 8 + 4 + q], ov = s_gb[rsub * 8 + 6 + q];
        float c = g_C0[rr][jh];
        g_H0[nxt][rr][jh] = cellupd(iv, fv, gv, ov, c);
        g_C0[rr][jh] = c;
      }
      __syncthreads();
    }
    gridbar(cnt, phase);
    // L1
    for (int rb = 0; rb < 16; ++rb) {
      int rsub = tid >> 3;
      int rr = rb * 64 + rsub;
      float acc = dot512(&g_H0[nxt][rr][0], s_wih1 + g2q * WST) +
                  dot512(&g_H1[cur][rr][0], s_whh1 + g2q * WST) + s_b1[g2q];
      s_gb[rsub * 8 + g2q] = acc;
      __syncthreads();
      if (gate == 0) {
        int jh = jh0 + q;
        float iv = s_gb[rsub * 8 + q], fv = s_gb[rsub * 8 + 2 + q];
        float gv = s_gb[rsub * 8 + 4 + q], ov = s_gb[rsub * 8 + 6 + q];
        float c = g_C1[rr][jh];
        g_H1[nxt][rr][jh] = cellupd(iv, fv, gv, ov, c);
        g_C1[rr][jh] = c;
      }
      __syncthreads();
    }
    gridbar(cnt, phase);
    // pred: u = H1[nxt] . w_out + b_out ; out[r][d] = u
    {
      int r = wg * 4 + (tid >> 7);
      int p = tid & 127;
      const float4* hp = (const float4*)&g_H1[nxt][r][0];
      const float4* wo = (const float4*)s_wout;
      float4 a = hp[p], w4 = wo[p];
      float pv = a.x * w4.x + a.y * w4.y + a.z * w4.z + a.w * w4.w;
      for (int off = 32; off; off >>= 1) pv += __shfl_down(pv, off);
      if ((tid & 63) == 0) s_red[tid >> 6] = pv;
      __syncthreads();
      if (p == 0) {
        float tot = s_red[(tid >> 7) * 2] + s_red[(tid >> 7) * 2 + 1] + b_out[0];
        g_u[r] = tot;
        out[r * HOR + d] = tot;
      }
    }
    gridbar(cnt, phase);
  }
}

extern "C" void kernel_launch(void* const* d_in, const int* in_sizes, int n_in,
                              void* d_out, int out_size, void* d_ws, size_t ws_size,
                              hipStream_t stream) {
  (void)in_sizes; (void)n_in; (void)out_size; (void)ws_size;
  // barrier counter lives at d_ws[0]; must start at 0 every call
  hipMemsetAsync(d_ws, 0, 256, stream);
  lstm_all<<<NWG, NT, 0, stream>>>(
      (const float*)d_in[0], (const float*)d_in[1], (const float*)d_in[2],
      (const float*)d_in[3], (const float*)d_in[4], (const float*)d_in[5],
      (const float*)d_in[6], (const float*)d_in[7], (const float*)d_in[8],
      (const float*)d_in[9], (float*)d_out, (unsigned*)d_ws);
}